// Round 1
// baseline (401.412 us; speedup 1.0000x reference)
//
#include <hip/hip_runtime.h>

#define NN 50000
#define NE 1600000
#define DF 64
#define DH 128

// ---------------- scatter: agg[row] += x[col] for row != col ----------------
// one wave handles one edge (64 lanes = 64 features): ei reads broadcast,
// x gather coalesced 256B, atomicAdd coalesced 256B.
__global__ __launch_bounds__(256) void k_scatter(const float* __restrict__ x,
                                                 const int* __restrict__ ei,
                                                 float* __restrict__ agg) {
    unsigned g = blockIdx.x * 256u + threadIdx.x;
    unsigned e = g >> 6;
    unsigned f = g & 63u;
    if (e >= NE) return;
    int r = ei[e];
    int c = ei[NE + e];
    if (r == c) return;  // remove_self_loops
    atomicAdd(&agg[(size_t)r * DF + f], x[(size_t)c * DF + f]);
}

// ---------------- fused (1+eps)*x + agg -> Linear(64,128) -> ReLU -> Linear(128,64) ----
// 16 rows per block, 256 threads, weights staged in LDS (64 KB), fp32 VALU.
#define ROWS 16
#define IN_STRIDE 68    // 64 + 4 pad: breaks 4-way bank conflict on row-broadcast reads
#define H_STRIDE 132    // 128 + 4 pad

__global__ __launch_bounds__(256) void k_mlp(const float* __restrict__ x,
                                             const float* __restrict__ agg,
                                             const float* __restrict__ w1,
                                             const float* __restrict__ b1,
                                             const float* __restrict__ w2,
                                             const float* __restrict__ b2,
                                             const float* __restrict__ eps,
                                             float* __restrict__ out) {
    __shared__ float w1s[DF * DH];          // 32 KB, w1[f][j] at f*128+j
    __shared__ float w2s[DH * DF];          // 32 KB, w2[j][c] at j*64+c
    __shared__ float in_s[ROWS * IN_STRIDE];
    __shared__ float h_s[ROWS * H_STRIDE];

    const int tid = threadIdx.x;
    const int row0 = blockIdx.x * ROWS;     // 50000 % 16 == 0 -> no bounds checks

    // stage weights (float4, coalesced)
    for (int i = tid; i < DF * DH / 4; i += 256)
        ((float4*)w1s)[i] = ((const float4*)w1)[i];
    for (int i = tid; i < DH * DF / 4; i += 256)
        ((float4*)w2s)[i] = ((const float4*)w2)[i];

    // stage input rows: in = (1+eps)*x + agg
    const float epsv = 1.0f + eps[0];
    {
        int r = tid >> 4, fq = tid & 15;    // 16 rows x 16 float4
        float4 xv = ((const float4*)x)[(size_t)(row0 + r) * 16 + fq];
        float4 av = ((const float4*)agg)[(size_t)(row0 + r) * 16 + fq];
        float4 v;
        v.x = epsv * xv.x + av.x;
        v.y = epsv * xv.y + av.y;
        v.z = epsv * xv.z + av.z;
        v.w = epsv * xv.w + av.w;
        *(float4*)(in_s + r * IN_STRIDE + fq * 4) = v;
    }
    __syncthreads();

    // h = relu(in @ w1 + b1): each thread does 2 rows x 4 hidden cols
    {
        const int jb = tid & 31;            // 32 j-groups of 4
        const int rp = tid >> 5;            // 8 row-pairs
        const int j0 = jb * 4;
        const int rA = rp * 2, rB = rp * 2 + 1;
        float4 b1v = *(const float4*)&b1[j0];
        float aA0 = b1v.x, aA1 = b1v.y, aA2 = b1v.z, aA3 = b1v.w;
        float aB0 = b1v.x, aB1 = b1v.y, aB2 = b1v.z, aB3 = b1v.w;
        const float* inA = in_s + rA * IN_STRIDE;
        const float* inB = in_s + rB * IN_STRIDE;
#pragma unroll 8
        for (int f = 0; f < DF; ++f) {
            float xa = inA[f];
            float xb = inB[f];
            float4 w = *(const float4*)&w1s[f * DH + j0];
            aA0 += xa * w.x; aA1 += xa * w.y; aA2 += xa * w.z; aA3 += xa * w.w;
            aB0 += xb * w.x; aB1 += xb * w.y; aB2 += xb * w.z; aB3 += xb * w.w;
        }
        float4 hA, hB;
        hA.x = fmaxf(aA0, 0.f); hA.y = fmaxf(aA1, 0.f);
        hA.z = fmaxf(aA2, 0.f); hA.w = fmaxf(aA3, 0.f);
        hB.x = fmaxf(aB0, 0.f); hB.y = fmaxf(aB1, 0.f);
        hB.z = fmaxf(aB2, 0.f); hB.w = fmaxf(aB3, 0.f);
        *(float4*)&h_s[rA * H_STRIDE + j0] = hA;
        *(float4*)&h_s[rB * H_STRIDE + j0] = hB;
    }
    __syncthreads();

    // out = h @ w2 + b2: each thread does 1 row x 4 out cols
    {
        const int r = tid >> 4;             // 16 rows
        const int c0 = (tid & 15) * 4;      // 16 c-groups of 4
        float4 b2v = *(const float4*)&b2[c0];
        float a0 = b2v.x, a1 = b2v.y, a2 = b2v.z, a3 = b2v.w;
        const float* hr = h_s + r * H_STRIDE;
#pragma unroll 4
        for (int j4 = 0; j4 < DH / 4; ++j4) {
            float4 hv = *(const float4*)&hr[j4 * 4];
            float4 w0 = *(const float4*)&w2s[(j4 * 4 + 0) * DF + c0];
            float4 w1v = *(const float4*)&w2s[(j4 * 4 + 1) * DF + c0];
            float4 w2v = *(const float4*)&w2s[(j4 * 4 + 2) * DF + c0];
            float4 w3v = *(const float4*)&w2s[(j4 * 4 + 3) * DF + c0];
            a0 += hv.x * w0.x + hv.y * w1v.x + hv.z * w2v.x + hv.w * w3v.x;
            a1 += hv.x * w0.y + hv.y * w1v.y + hv.z * w2v.y + hv.w * w3v.y;
            a2 += hv.x * w0.z + hv.y * w1v.z + hv.z * w2v.z + hv.w * w3v.z;
            a3 += hv.x * w0.w + hv.y * w1v.w + hv.z * w2v.w + hv.w * w3v.w;
        }
        float4 o; o.x = a0; o.y = a1; o.z = a2; o.w = a3;
        *(float4*)&out[(size_t)(row0 + r) * DF + c0] = o;
    }
}

extern "C" void kernel_launch(void* const* d_in, const int* in_sizes, int n_in,
                              void* d_out, int out_size, void* d_ws, size_t ws_size,
                              hipStream_t stream) {
    const float* x   = (const float*)d_in[0];
    const int*   ei  = (const int*)d_in[1];
    const float* w1  = (const float*)d_in[2];
    const float* b1  = (const float*)d_in[3];
    const float* w2  = (const float*)d_in[4];
    const float* b2  = (const float*)d_in[5];
    const float* eps = (const float*)d_in[6];
    float* out = (float*)d_out;

    float* agg = (float*)d_ws;  // NN*DF floats = 12.8 MB

    hipMemsetAsync(agg, 0, (size_t)NN * DF * sizeof(float), stream);

    // scatter: one wave per edge -> NE/4 blocks of 256
    k_scatter<<<NE / 4, 256, 0, stream>>>(x, ei, agg);

    // fused residual + MLP: 16 rows per block
    k_mlp<<<NN / ROWS, 256, 0, stream>>>(x, agg, w1, b1, w2, b2, eps, out);
}

// Round 2
// 331.093 us; speedup vs baseline: 1.2124x; 1.2124x over previous
//
#include <hip/hip_runtime.h>

#define NN 50000
#define NE 1600000
#define DF 64
#define DH 128

// ===================== CSR build =====================
// ws layout: deg[NN] | rowptr[NN] | cursor[NN] | colidx[NE]

__global__ __launch_bounds__(256) void k_degree(const int* __restrict__ ei,
                                                int* __restrict__ deg) {
    unsigned e = blockIdx.x * 256u + threadIdx.x;
    if (e >= NE) return;
    int r = ei[e];
    int c = ei[NE + e];
    if (r != c) atomicAdd(&deg[r], 1);
}

// single-block tiled exclusive scan over NN degrees -> rowptr (and cursor copy)
__global__ __launch_bounds__(1024) void k_scan(const int* __restrict__ deg,
                                               int* __restrict__ rowptr,
                                               int* __restrict__ cursor) {
    __shared__ int wsum[16];
    __shared__ int s_running;
    const int tid = threadIdx.x;
    const int lane = tid & 63, wid = tid >> 6;
    if (tid == 0) s_running = 0;
    __syncthreads();

    for (int base = 0; base < NN; base += 8192) {
        const int idx0 = base + tid * 8;
        int v[8];
        int local = 0;
#pragma unroll
        for (int i = 0; i < 8; ++i) {
            int idx = idx0 + i;
            int d = (idx < NN) ? deg[idx] : 0;
            v[i] = local;           // exclusive within thread
            local += d;
        }
        // wave-inclusive scan of thread totals
        int xi = local;
#pragma unroll
        for (int off = 1; off < 64; off <<= 1) {
            int y = __shfl_up(xi, off, 64);
            if (lane >= off) xi += y;
        }
        if (lane == 63) wsum[wid] = xi;
        __syncthreads();
        if (wid == 0 && lane < 16) {
            int w = wsum[lane];
#pragma unroll
            for (int off = 1; off < 16; off <<= 1) {
                int y = __shfl_up(w, off, 64);
                if (lane >= off) w += y;
            }
            wsum[lane] = w;         // inclusive wave prefix
        }
        __syncthreads();
        const int wave_excl = (wid == 0) ? 0 : wsum[wid - 1];
        const int gbase = s_running + wave_excl + (xi - local);
#pragma unroll
        for (int i = 0; i < 8; ++i) {
            int idx = idx0 + i;
            if (idx < NN) {
                int p = gbase + v[i];
                rowptr[idx] = p;
                cursor[idx] = p;
            }
        }
        __syncthreads();
        if (tid == 0) s_running += wsum[15];
        __syncthreads();
    }
}

__global__ __launch_bounds__(256) void k_fill(const int* __restrict__ ei,
                                              int* __restrict__ cursor,
                                              int* __restrict__ colidx) {
    unsigned e = blockIdx.x * 256u + threadIdx.x;
    if (e >= NE) return;
    int r = ei[e];
    int c = ei[NE + e];
    if (r != c) {
        int p = atomicAdd(&cursor[r], 1);
        colidx[p] = c;
    }
}

// ===================== gather: in = (1+eps)*x + sum_{c in N(n)} x[c] =====================
// one wave per node; lane = feature. After k_fill, cursor[n] == end offset.
__global__ __launch_bounds__(256) void k_gather(const float* __restrict__ x,
                                                const int* __restrict__ rowptr,
                                                const int* __restrict__ rowend,
                                                const int* __restrict__ colidx,
                                                const float* __restrict__ eps,
                                                float* __restrict__ inbuf) {
    unsigned g = blockIdx.x * 256u + threadIdx.x;
    unsigned n = g >> 6;
    unsigned f = g & 63u;
    if (n >= NN) return;
    int k = rowptr[n];
    const int e = rowend[n];
    float acc = 0.f;
    // 4-deep pipelined gather (ILP to hide L2/L3 latency)
    for (; k + 4 <= e; k += 4) {
        int c0 = colidx[k], c1 = colidx[k + 1], c2 = colidx[k + 2], c3 = colidx[k + 3];
        float v0 = x[(size_t)c0 * DF + f];
        float v1 = x[(size_t)c1 * DF + f];
        float v2 = x[(size_t)c2 * DF + f];
        float v3 = x[(size_t)c3 * DF + f];
        acc += v0; acc += v1; acc += v2; acc += v3;
    }
    for (; k < e; ++k) acc += x[(size_t)colidx[k] * DF + f];
    inbuf[(size_t)n * DF + f] = (1.0f + eps[0]) * x[(size_t)n * DF + f] + acc;
}

// ===================== fused MLP: in -> Linear(64,128) -> ReLU -> Linear(128,64) =====================
// reads `io` rows, writes same rows (per-block ownership; barrier between).
#define ROWS 16
#define IN_STRIDE 68
#define H_STRIDE 132

__global__ __launch_bounds__(256) void k_mlp(float* io,
                                             const float* __restrict__ w1,
                                             const float* __restrict__ b1,
                                             const float* __restrict__ w2,
                                             const float* __restrict__ b2) {
    __shared__ float w1s[DF * DH];
    __shared__ float w2s[DH * DF];
    __shared__ float in_s[ROWS * IN_STRIDE];
    __shared__ float h_s[ROWS * H_STRIDE];

    const int tid = threadIdx.x;
    const int row0 = blockIdx.x * ROWS;

    for (int i = tid; i < DF * DH / 4; i += 256)
        ((float4*)w1s)[i] = ((const float4*)w1)[i];
    for (int i = tid; i < DH * DF / 4; i += 256)
        ((float4*)w2s)[i] = ((const float4*)w2)[i];

    {
        int r = tid >> 4, fq = tid & 15;
        float4 v = ((const float4*)io)[(size_t)(row0 + r) * 16 + fq];
        *(float4*)(in_s + r * IN_STRIDE + fq * 4) = v;
    }
    __syncthreads();

    {
        const int jb = tid & 31;
        const int rp = tid >> 5;
        const int j0 = jb * 4;
        const int rA = rp * 2, rB = rp * 2 + 1;
        float4 b1v = *(const float4*)&b1[j0];
        float aA0 = b1v.x, aA1 = b1v.y, aA2 = b1v.z, aA3 = b1v.w;
        float aB0 = b1v.x, aB1 = b1v.y, aB2 = b1v.z, aB3 = b1v.w;
        const float* inA = in_s + rA * IN_STRIDE;
        const float* inB = in_s + rB * IN_STRIDE;
#pragma unroll 8
        for (int f = 0; f < DF; ++f) {
            float xa = inA[f];
            float xb = inB[f];
            float4 w = *(const float4*)&w1s[f * DH + j0];
            aA0 += xa * w.x; aA1 += xa * w.y; aA2 += xa * w.z; aA3 += xa * w.w;
            aB0 += xb * w.x; aB1 += xb * w.y; aB2 += xb * w.z; aB3 += xb * w.w;
        }
        float4 hA, hB;
        hA.x = fmaxf(aA0, 0.f); hA.y = fmaxf(aA1, 0.f);
        hA.z = fmaxf(aA2, 0.f); hA.w = fmaxf(aA3, 0.f);
        hB.x = fmaxf(aB0, 0.f); hB.y = fmaxf(aB1, 0.f);
        hB.z = fmaxf(aB2, 0.f); hB.w = fmaxf(aB3, 0.f);
        *(float4*)&h_s[rA * H_STRIDE + j0] = hA;
        *(float4*)&h_s[rB * H_STRIDE + j0] = hB;
    }
    __syncthreads();

    {
        const int r = tid >> 4;
        const int c0 = (tid & 15) * 4;
        float4 b2v = *(const float4*)&b2[c0];
        float a0 = b2v.x, a1 = b2v.y, a2 = b2v.z, a3 = b2v.w;
        const float* hr = h_s + r * H_STRIDE;
#pragma unroll 4
        for (int j4 = 0; j4 < DH / 4; ++j4) {
            float4 hv = *(const float4*)&hr[j4 * 4];
            float4 w0 = *(const float4*)&w2s[(j4 * 4 + 0) * DF + c0];
            float4 w1v = *(const float4*)&w2s[(j4 * 4 + 1) * DF + c0];
            float4 w2v = *(const float4*)&w2s[(j4 * 4 + 2) * DF + c0];
            float4 w3v = *(const float4*)&w2s[(j4 * 4 + 3) * DF + c0];
            a0 += hv.x * w0.x + hv.y * w1v.x + hv.z * w2v.x + hv.w * w3v.x;
            a1 += hv.x * w0.y + hv.y * w1v.y + hv.z * w2v.y + hv.w * w3v.y;
            a2 += hv.x * w0.z + hv.y * w1v.z + hv.z * w2v.z + hv.w * w3v.z;
            a3 += hv.x * w0.w + hv.y * w1v.w + hv.z * w2v.w + hv.w * w3v.w;
        }
        float4 o; o.x = a0; o.y = a1; o.z = a2; o.w = a3;
        *(float4*)&io[(size_t)(row0 + r) * DF + c0] = o;
    }
}

extern "C" void kernel_launch(void* const* d_in, const int* in_sizes, int n_in,
                              void* d_out, int out_size, void* d_ws, size_t ws_size,
                              hipStream_t stream) {
    const float* x   = (const float*)d_in[0];
    const int*   ei  = (const int*)d_in[1];
    const float* w1  = (const float*)d_in[2];
    const float* b1  = (const float*)d_in[3];
    const float* w2  = (const float*)d_in[4];
    const float* b2  = (const float*)d_in[5];
    const float* eps = (const float*)d_in[6];
    float* out = (float*)d_out;

    int* deg    = (int*)d_ws;
    int* rowptr = deg + NN;
    int* cursor = rowptr + NN;
    int* colidx = cursor + NN;

    hipMemsetAsync(deg, 0, (size_t)NN * sizeof(int), stream);

    k_degree<<<(NE + 255) / 256, 256, 0, stream>>>(ei, deg);
    k_scan<<<1, 1024, 0, stream>>>(deg, rowptr, cursor);
    k_fill<<<(NE + 255) / 256, 256, 0, stream>>>(ei, cursor, colidx);

    // gather writes in = (1+eps)x + agg directly into d_out (temp reuse)
    k_gather<<<(NN * 64 + 255) / 256, 256, 0, stream>>>(x, rowptr, cursor, colidx, eps, out);

    // MLP in place over d_out
    k_mlp<<<NN / ROWS, 256, 0, stream>>>(out, w1, b1, w2, b2);
}

// Round 4
// 314.641 us; speedup vs baseline: 1.2758x; 1.0523x over previous
//
#include <hip/hip_runtime.h>

#define NN 50000
#define NE 1600000
#define DF 64
#define DH 128

// ws layout (bytes):
//   cur     : int[NN+1]   @ 0        (200,004 B, padded to 200,064)
//   colidx16: ushort[NE]  @ 200,064  (3,200,000 B)
//   xb      : ushort[NN*DF] @ 3,400,064 (6,400,000 B)
// total 9.8 MB (< 12.8 MB budget proven in round 1)

__device__ __forceinline__ unsigned short f2bf(float f) {
    unsigned u = __float_as_uint(f);
    unsigned r = (u + 0x7FFFu + ((u >> 16) & 1u)) >> 16;  // RNE
    return (unsigned short)r;
}
__device__ __forceinline__ float bf2f(unsigned short h) {
    return __uint_as_float((unsigned)h << 16);
}

// ---------- cast x (f32) -> xb (bf16 raw) ----------
__global__ __launch_bounds__(256) void k_cast(const float* __restrict__ x,
                                              ushort* __restrict__ xb) {
    unsigned i = blockIdx.x * 256u + threadIdx.x;   // over NN*DF/4 float4s
    if (i >= NN * DF / 4) return;
    float4 v = ((const float4*)x)[i];
    ushort4 o;
    o.x = f2bf(v.x); o.y = f2bf(v.y); o.z = f2bf(v.z); o.w = f2bf(v.w);
    ((ushort4*)xb)[i] = o;
}

// ---------- degree count into cur[0..NN) ----------
__global__ __launch_bounds__(256) void k_degree(const int* __restrict__ ei,
                                                int* __restrict__ cur) {
    unsigned e = blockIdx.x * 256u + threadIdx.x;
    if (e >= NE) return;
    int r = ei[e];
    int c = ei[NE + e];
    if (r != c) atomicAdd(&cur[r], 1);
}

// ---------- in-place inclusive scan: cur[n] = sum_{m<=n} deg[m]; cur[NN] = K ----------
__global__ __launch_bounds__(1024) void k_scan(int* __restrict__ cur) {
    __shared__ int wsum[16];
    __shared__ int s_running;
    const int tid = threadIdx.x;
    const int lane = tid & 63, wid = tid >> 6;
    if (tid == 0) s_running = 0;
    __syncthreads();

    for (int base = 0; base < NN; base += 8192) {
        const int idx0 = base + tid * 8;
        int v[8];
        int local = 0;
#pragma unroll
        for (int i = 0; i < 8; ++i) {
            int idx = idx0 + i;
            int d = (idx < NN) ? cur[idx] : 0;
            local += d;
            v[i] = local;                 // inclusive within thread
        }
        int xi = local;
#pragma unroll
        for (int off = 1; off < 64; off <<= 1) {
            int y = __shfl_up(xi, off, 64);
            if (lane >= off) xi += y;
        }
        if (lane == 63) wsum[wid] = xi;
        __syncthreads();
        if (wid == 0 && lane < 16) {
            int w = wsum[lane];
#pragma unroll
            for (int off = 1; off < 16; off <<= 1) {
                int y = __shfl_up(w, off, 64);
                if (lane >= off) w += y;
            }
            wsum[lane] = w;
        }
        __syncthreads();
        const int wave_excl = (wid == 0) ? 0 : wsum[wid - 1];
        const int gbase = s_running + wave_excl + (xi - local);
#pragma unroll
        for (int i = 0; i < 8; ++i) {
            int idx = idx0 + i;
            if (idx < NN) cur[idx] = gbase + v[i];
        }
        __syncthreads();
        if (tid == 0) s_running += wsum[15];
        __syncthreads();
    }
    if (tid == 0) cur[NN] = s_running;    // sentinel: end of last row
}

// ---------- reverse fill: after this, cur[n] = row-start, cur[n+1] = row-end ----------
__global__ __launch_bounds__(256) void k_fill(const int* __restrict__ ei,
                                              int* __restrict__ cur,
                                              ushort* __restrict__ colidx16) {
    unsigned e = blockIdx.x * 256u + threadIdx.x;
    if (e >= NE) return;
    int r = ei[e];
    int c = ei[NE + e];
    if (r != c) {
        int p = atomicSub(&cur[r], 1);
        colidx16[p - 1] = (unsigned short)c;
    }
}

// ---------- gather: out = (1+eps)*x[n] + sum over neighbors (bf16 rows) ----------
__global__ __launch_bounds__(256) void k_gather(const float* __restrict__ x,
                                                const ushort* __restrict__ xb,
                                                const int* __restrict__ cur,
                                                const ushort* __restrict__ colidx16,
                                                const float* __restrict__ eps,
                                                float* __restrict__ outbuf) {
    unsigned g = blockIdx.x * 256u + threadIdx.x;
    unsigned n = g >> 6;
    unsigned f = g & 63u;
    if (n >= NN) return;
    int k = cur[n];          // start (post-fill)
    const int e = cur[n + 1];  // end
    float acc = 0.f;
    for (; k + 4 <= e; k += 4) {
        int c0 = colidx16[k], c1 = colidx16[k + 1], c2 = colidx16[k + 2], c3 = colidx16[k + 3];
        float v0 = bf2f(xb[(size_t)c0 * DF + f]);
        float v1 = bf2f(xb[(size_t)c1 * DF + f]);
        float v2 = bf2f(xb[(size_t)c2 * DF + f]);
        float v3 = bf2f(xb[(size_t)c3 * DF + f]);
        acc += v0; acc += v1; acc += v2; acc += v3;
    }
    for (; k < e; ++k) acc += bf2f(xb[(size_t)colidx16[k] * DF + f]);
    outbuf[(size_t)n * DF + f] = (1.0f + eps[0]) * x[(size_t)n * DF + f] + acc;
}

// ---------- fused MLP (unchanged, proven) ----------
#define ROWS 16
#define IN_STRIDE 68
#define H_STRIDE 132

__global__ __launch_bounds__(256) void k_mlp(float* io,
                                             const float* __restrict__ w1,
                                             const float* __restrict__ b1,
                                             const float* __restrict__ w2,
                                             const float* __restrict__ b2) {
    __shared__ float w1s[DF * DH];
    __shared__ float w2s[DH * DF];
    __shared__ float in_s[ROWS * IN_STRIDE];
    __shared__ float h_s[ROWS * H_STRIDE];

    const int tid = threadIdx.x;
    const int row0 = blockIdx.x * ROWS;

    for (int i = tid; i < DF * DH / 4; i += 256)
        ((float4*)w1s)[i] = ((const float4*)w1)[i];
    for (int i = tid; i < DH * DF / 4; i += 256)
        ((float4*)w2s)[i] = ((const float4*)w2)[i];

    {
        int r = tid >> 4, fq = tid & 15;
        float4 v = ((const float4*)io)[(size_t)(row0 + r) * 16 + fq];
        *(float4*)(in_s + r * IN_STRIDE + fq * 4) = v;
    }
    __syncthreads();

    {
        const int jb = tid & 31;
        const int rp = tid >> 5;
        const int j0 = jb * 4;
        const int rA = rp * 2, rB = rp * 2 + 1;
        float4 b1v = *(const float4*)&b1[j0];
        float aA0 = b1v.x, aA1 = b1v.y, aA2 = b1v.z, aA3 = b1v.w;
        float aB0 = b1v.x, aB1 = b1v.y, aB2 = b1v.z, aB3 = b1v.w;
        const float* inA = in_s + rA * IN_STRIDE;
        const float* inB = in_s + rB * IN_STRIDE;
#pragma unroll 8
        for (int f = 0; f < DF; ++f) {
            float xa = inA[f];
            float xb_ = inB[f];
            float4 w = *(const float4*)&w1s[f * DH + j0];
            aA0 += xa * w.x; aA1 += xa * w.y; aA2 += xa * w.z; aA3 += xa * w.w;
            aB0 += xb_ * w.x; aB1 += xb_ * w.y; aB2 += xb_ * w.z; aB3 += xb_ * w.w;
        }
        float4 hA, hB;
        hA.x = fmaxf(aA0, 0.f); hA.y = fmaxf(aA1, 0.f);
        hA.z = fmaxf(aA2, 0.f); hA.w = fmaxf(aA3, 0.f);
        hB.x = fmaxf(aB0, 0.f); hB.y = fmaxf(aB1, 0.f);
        hB.z = fmaxf(aB2, 0.f); hB.w = fmaxf(aB3, 0.f);
        *(float4*)&h_s[rA * H_STRIDE + j0] = hA;
        *(float4*)&h_s[rB * H_STRIDE + j0] = hB;
    }
    __syncthreads();

    {
        const int r = tid >> 4;
        const int c0 = (tid & 15) * 4;
        float4 b2v = *(const float4*)&b2[c0];
        float a0 = b2v.x, a1 = b2v.y, a2 = b2v.z, a3 = b2v.w;
        const float* hr = h_s + r * H_STRIDE;
#pragma unroll 4
        for (int j4 = 0; j4 < DH / 4; ++j4) {
            float4 hv = *(const float4*)&hr[j4 * 4];
            float4 w0 = *(const float4*)&w2s[(j4 * 4 + 0) * DF + c0];
            float4 w1v = *(const float4*)&w2s[(j4 * 4 + 1) * DF + c0];
            float4 w2v = *(const float4*)&w2s[(j4 * 4 + 2) * DF + c0];
            float4 w3v = *(const float4*)&w2s[(j4 * 4 + 3) * DF + c0];
            a0 += hv.x * w0.x + hv.y * w1v.x + hv.z * w2v.x + hv.w * w3v.x;
            a1 += hv.x * w0.y + hv.y * w1v.y + hv.z * w2v.y + hv.w * w3v.y;
            a2 += hv.x * w0.z + hv.y * w1v.z + hv.z * w2v.z + hv.w * w3v.z;
            a3 += hv.x * w0.w + hv.y * w1v.w + hv.z * w2v.w + hv.w * w3v.w;
        }
        float4 o; o.x = a0; o.y = a1; o.z = a2; o.w = a3;
        *(float4*)&io[(size_t)(row0 + r) * DF + c0] = o;
    }
}

extern "C" void kernel_launch(void* const* d_in, const int* in_sizes, int n_in,
                              void* d_out, int out_size, void* d_ws, size_t ws_size,
                              hipStream_t stream) {
    const float* x   = (const float*)d_in[0];
    const int*   ei  = (const int*)d_in[1];
    const float* w1  = (const float*)d_in[2];
    const float* b1  = (const float*)d_in[3];
    const float* w2  = (const float*)d_in[4];
    const float* b2  = (const float*)d_in[5];
    const float* eps = (const float*)d_in[6];
    float* out = (float*)d_out;

    int*    cur      = (int*)d_ws;
    ushort* colidx16 = (ushort*)((char*)d_ws + 200064);
    ushort* xb       = (ushort*)((char*)d_ws + 3400064);

    hipMemsetAsync(cur, 0, (size_t)(NN + 1) * sizeof(int), stream);

    k_cast<<<NN * DF / 4 / 256, 256, 0, stream>>>(x, xb);
    k_degree<<<(NE + 255) / 256, 256, 0, stream>>>(ei, cur);
    k_scan<<<1, 1024, 0, stream>>>(cur);
    k_fill<<<(NE + 255) / 256, 256, 0, stream>>>(ei, cur, colidx16);
    k_gather<<<NN * 64 / 256, 256, 0, stream>>>(x, xb, cur, colidx16, eps, out);
    k_mlp<<<NN / ROWS, 256, 0, stream>>>(out, w1, b1, w2, b2);
}